// Round 1
// baseline (483.006 us; speedup 1.0000x reference)
//
#include <hip/hip_runtime.h>
#include <math.h>

#define BB_ 32   // batch
#define PP_ 24   // sentences
#define SS_ 48   // tokens
#define HH_ 512  // hidden
#define FF_ 64   // feature
#define DD_ 576  // H+F
#define G4_ 2048 // 4H

typedef __attribute__((ext_vector_type(8))) short short8;
typedef __attribute__((ext_vector_type(4))) float f32x4;

__device__ __forceinline__ float sigf(float x) { return 1.f / (1.f + expf(-x)); }

__device__ __forceinline__ unsigned short f2bf(float f) {
    unsigned int u = __float_as_uint(f);
    u += 0x7FFFu + ((u >> 16) & 1u);     // RNE
    return (unsigned short)(u >> 16);
}

// ---------------------------------------------------------------------------
// LAUNCH 1: fused [attn | weight prep | zeroing]. grid 2465 x 256.
//  blk [0,768):     attention+pooling (inline mask-dtype detect, valid-token
//                   compaction: masked rows never touch HBM)
//  blk [768,1280):  Whh_f -> bf16 B-fragment order (16-block fwd tiling:
//                   [nb(16)][j(8)][ks(16)][lane(64)] 16B frags,
//                   n = (j>>1)*512 + nb*32 + (j&1)*16 + (lane&15),
//                   k0 = ks*32 + (lane>>4)*8)
//  blk [1280,2432): Wih_f -> bf16 row-major
//  blk [2432,2464): zero AfA (h0 fragments)
//  blk 2464:        zero lstm barrier flags
// ---------------------------------------------------------------------------
__global__ void __launch_bounds__(256) prep_attn_kernel(
        const int* __restrict__ x, const unsigned int* __restrict__ maskw,
        const float* __restrict__ x_feature, const float* __restrict__ emb,
        const float* __restrict__ w_attn, const float* __restrict__ b_attn,
        const float* __restrict__ Whh, unsigned short* __restrict__ Bf,
        const float* __restrict__ Wih, unsigned short* __restrict__ Wbf,
        float* __restrict__ AfA, int* __restrict__ flags,
        float* __restrict__ seq)
{
    int blk = blockIdx.x, tid = threadIdx.x;
    if (blk < 768) {
        __shared__ float sc_s[SS_], alpha_s[SS_];
        __shared__ int vtok[SS_], vpos[SS_];
        __shared__ int nv_s, s_u8, s_f32;
        __shared__ int idx_s[SS_];
        __shared__ unsigned char msk_s[SS_];
        if (tid == 0) { s_u8 = 0; s_f32 = 0; }
        __syncthreads();
        int u8 = 0, f32 = 0;
        for (int i = tid; i < 9216; i += 256) {     // mask dtype detect (L2-hot)
            unsigned int w = maskw[i];
            if (w == 0x3F800000u) f32 = 1;
            else if (w > 1u) u8 = 1;
        }
        if (u8) s_u8 = 1;
        if (f32) s_f32 = 1;
        __syncthreads();
        int mode = s_f32 ? 2 : (s_u8 ? 1 : 0);
        int bp = blk, b = bp / PP_, p = bp % PP_;
        if (tid < SS_) {
            size_t i = (size_t)bp * SS_ + tid;
            idx_s[tid] = x[i];
            unsigned char mv;
            if (mode == 1)      mv = ((const unsigned char*)maskw)[i];
            else if (mode == 2) mv = (((const float*)maskw)[i] != 0.f);
            else                mv = (((const int*)maskw)[i] != 0);
            msk_s[tid] = mv;
        }
        __syncthreads();
        if (tid == 0) {                              // compact valid tokens
            int nv = 0;
            for (int s = 0; s < SS_; ++s)
                if (!msk_s[s]) { vtok[nv] = idx_s[s]; vpos[nv] = s; ++nv; }
            nv_s = nv;
        }
        __syncthreads();
        int nv = nv_s;
        int wave = tid >> 6, lane = tid & 63;
        float4 wa0 = ((const float4*)w_attn)[lane];        // regs, no LDS bank hits
        float4 wa1 = ((const float4*)w_attn)[64 + lane];
        for (int j = wave; j < nv; j += 4) {
            const float4* er4 = (const float4*)(emb + (size_t)vtok[j] * HH_);
            float4 v0 = er4[lane], v1 = er4[64 + lane];    // coalesced full row
            float acc = v0.x * wa0.x + v0.y * wa0.y + v0.z * wa0.z + v0.w * wa0.w
                      + v1.x * wa1.x + v1.y * wa1.y + v1.z * wa1.z + v1.w * wa1.w;
            #pragma unroll
            for (int off = 32; off > 0; off >>= 1) acc += __shfl_down(acc, off, 64);
            if (lane == 0) sc_s[j] = acc + b_attn[0];
        }
        __syncthreads();
        if (tid == 0) {                              // softmax over valid subset
            float m = -3.4e38f;
            for (int j = 0; j < nv; ++j) if (sc_s[j] > m) m = sc_s[j];
            float sum = 0.f;
            for (int j = 0; j < nv; ++j) { float a = expf(sc_s[j] - m); alpha_s[j] = a; sum += a; }
            float inv = (nv > 0) ? (1.f / sum) : 0.f;
            for (int j = 0; j < nv; ++j) alpha_s[j] *= inv;
        }
        __syncthreads();
        float acc0 = 0.f, acc1 = 0.f;
        for (int j = 0; j < nv; ++j) {               // branch-free, pipelines
            float a = alpha_s[j];
            const float* er = emb + (size_t)vtok[j] * HH_;
            acc0 += a * er[tid];
            acc1 += a * er[tid + 256];
        }
        float* orow = seq + ((size_t)p * BB_ + b) * DD_;
        orow[tid] = acc0;
        orow[tid + 256] = acc1;
        if (tid < FF_) {
            float accF = 0.f;
            for (int j = 0; j < nv; ++j)
                accF += x_feature[((size_t)bp * SS_ + vpos[j]) * FF_ + tid];
            orow[HH_ + tid] = accF;
        }
    } else if (blk < 1280) {
        // Whh -> B-fragment order for the 16-block persistent fwd LSTM.
        int idx = (blk - 768) * 256 + tid;          // [0, 131072)
        int lane = idx & 63;
        int ks = (idx >> 6) & 15;
        int j = (idx >> 10) & 7;                    // j = g*2 + tt
        int nb = idx >> 13;                         // [0,16)
        int c = lane & 15, q = lane >> 4;
        int g = j >> 1, tt = j & 1;
        int nrow = g * HH_ + nb * 32 + tt * 16 + c; // gate-row in Whh
        int k0 = ks * 32 + q * 8;
        const float* src = Whh + (size_t)nrow * HH_ + k0;
        unsigned int w0 = (unsigned int)f2bf(src[0]) | ((unsigned int)f2bf(src[1]) << 16);
        unsigned int w1 = (unsigned int)f2bf(src[2]) | ((unsigned int)f2bf(src[3]) << 16);
        unsigned int w2 = (unsigned int)f2bf(src[4]) | ((unsigned int)f2bf(src[5]) << 16);
        unsigned int w3 = (unsigned int)f2bf(src[6]) | ((unsigned int)f2bf(src[7]) << 16);
        *(uint4*)(Bf + (size_t)idx * 8) = make_uint4(w0, w1, w2, w3);
    } else if (blk < 2432) {
        int i = (blk - 1280) * 256 + tid;           // Wih -> bf16 (294912 x4)
        float4 v = ((const float4*)Wih)[i];
        ushort4 o;
        o.x = f2bf(v.x); o.y = f2bf(v.y); o.z = f2bf(v.z); o.w = f2bf(v.w);
        ((ushort4*)Wbf)[i] = o;
    } else if (blk < 2464) {
        int idx = (blk - 2432) * 256 + tid;
        if (idx < 8192) AfA[idx] = 0.f;             // h0 fragments = 0
    } else {
        if (tid < 64) flags[tid] = 0;
    }
}

// ---------------------------------------------------------------------------
// LAUNCH 2: input-gate GEMM via MFMA bf16 (unchanged math).
// ---------------------------------------------------------------------------
__global__ void __launch_bounds__(256) in_gates_mfma_kernel(
        const float* __restrict__ A,
        const unsigned short* __restrict__ Wbf,
        const float* __restrict__ bih,
        const float* __restrict__ bhh,
        float* __restrict__ Cout)
{
    int tid = threadIdx.x, lane = tid & 63, w = tid >> 6;
    int m0 = blockIdx.y * 16;
    int nb = blockIdx.x * 128 + w * 32;
    int c = lane & 15, q = lane >> 4;
    const float* Ap = A + (size_t)(m0 + c) * DD_ + q * 8;
    const unsigned short* Bp0 = Wbf + (size_t)(nb + c) * DD_ + q * 8;
    const unsigned short* Bp1 = Bp0 + 16 * DD_;
    f32x4 acc0 = {0.f, 0.f, 0.f, 0.f}, acc1 = {0.f, 0.f, 0.f, 0.f};
    for (int k = 0; k < DD_; k += 32) {
        float4 alo = *(const float4*)(Ap + k);
        float4 ahi = *(const float4*)(Ap + k + 4);
        short8 a;
        a[0] = (short)f2bf(alo.x); a[1] = (short)f2bf(alo.y);
        a[2] = (short)f2bf(alo.z); a[3] = (short)f2bf(alo.w);
        a[4] = (short)f2bf(ahi.x); a[5] = (short)f2bf(ahi.y);
        a[6] = (short)f2bf(ahi.z); a[7] = (short)f2bf(ahi.w);
        short8 b0 = *(const short8*)(Bp0 + k);
        short8 b1 = *(const short8*)(Bp1 + k);
        acc0 = __builtin_amdgcn_mfma_f32_16x16x32_bf16(a, b0, acc0, 0, 0, 0);
        acc1 = __builtin_amdgcn_mfma_f32_16x16x32_bf16(a, b1, acc1, 0, 0, 0);
    }
    #pragma unroll
    for (int r = 0; r < 4; ++r) {
        int m = m0 + q * 4 + r;
        int n0 = nb + c, n1 = nb + 16 + c;
        Cout[(size_t)m * G4_ + n0] = acc0[r] + bih[n0] + bhh[n0];
        Cout[(size_t)m * G4_ + n1] = acc1[r] + bih[n1] + bhh[n1];
    }
}

// ---------------------------------------------------------------------------
// LAUNCH 3: fused [persistent fwd LSTM | backward one-step]. grid 80 x 256.
//  blk [0,16):   persistent LSTM, 16-block tiling:
//                block nb owns 32 hidden units = A-fragment k-slice ks==nb.
//                Wave (mt = wv&1, h2 = wv>>1) holds 4 B-tiles (256 VGPR,
//                1 wave/SIMD via __launch_bounds__(256,1) -> 512-reg budget).
//                Ain fused into MFMA acc init. Elementwise thread mapping ==
//                fragment store layout -> h packs straight from registers
//                (no LDS hstage, one less __syncthreads on critical path).
//                Barrier fan-in 16 (was 64).
//  blk [16,80):  backward-LSTM collapsed single step (unchanged).
// All 80 blocks co-resident (2 blocks/CU at 76 KB LDS) -> no deadlock.
// ---------------------------------------------------------------------------
__global__ void __launch_bounds__(256, 1) lstm_bwd_kernel(
        unsigned short* __restrict__ AfA, unsigned short* __restrict__ AfB,
        float* __restrict__ hbuf, const float* __restrict__ Ain,
        const unsigned short* __restrict__ Bfrag, int* __restrict__ flags,
        const float* __restrict__ seq, const int* __restrict__ lens,
        const float* __restrict__ Wih_b, const float* __restrict__ bih_b,
        const float* __restrict__ bhh_b, float* __restrict__ hbw)
{
    __shared__ float smem[19040];   // union: lstm {gl 128*33} | bwd {xsT 19008f + pl}
    int tid = threadIdx.x;
    if (blockIdx.x < 16) {
        float* gl = smem;                            // [128][33]: gate,unit x batch
        int lane = tid & 63, wv = tid >> 6;
        int mt = wv & 1, h2 = wv >> 1;               // wave: batch-half, gate-half
        int nb = blockIdx.x;
        int c = lane & 15, q = lane >> 4;
        // B fragments: 4 tiles per wave, register-resident for all 24 steps.
        short8 bfr[4][16];
        {
            const short8* Bp = (const short8*)Bfrag;
            #pragma unroll
            for (int jj = 0; jj < 4; ++jj) {
                const short8* bp = Bp + ((size_t)(nb * 8 + h2 * 4 + jj) * 16) * 64 + lane;
                #pragma unroll
                for (int ks = 0; ks < 16; ++ks) bfr[jj][ks] = bp[(size_t)ks * 64];
            }
        }
        // Elementwise ownership == fragment store layout:
        //   tid -> (mt_e, le, half): batch be, 4 consecutive units ue0..ue0+3,
        //   which is exactly one 8-byte half of one 16B fragment chunk at
        //   (mt_e, ks==nb, lane==le).
        int mt_e = tid >> 7, le = (tid >> 1) & 63, half = tid & 1;
        int be = mt_e * 16 + (le & 15);
        int ue0 = (le >> 4) * 8 + half * 4;
        float creg[4] = {0.f, 0.f, 0.f, 0.f};
        for (int t = 0; t < PP_; ++t) {
            const unsigned short* Af = (t & 1) ? AfB : AfA;
            unsigned short* An       = (t & 1) ? AfA : AfB;
            const float* Ain_t = Ain + (size_t)t * BB_ * G4_;
            // acc init = precomputed input gates (C-in layout matches exactly)
            f32x4 acc[4];
            #pragma unroll
            for (int jj = 0; jj < 4; ++jj) {
                int g = h2 * 2 + (jj >> 1), tt = jj & 1;
                int n = g * HH_ + nb * 32 + tt * 16 + c;
                #pragma unroll
                for (int r = 0; r < 4; ++r)
                    acc[jj][r] = Ain_t[(size_t)(mt * 16 + q * 4 + r) * G4_ + n];
            }
            // h fragments (uncached agent-scope: cross-XCD fresh)
            const unsigned long long* Ap64 =
                (const unsigned long long*)Af + (size_t)mt * 2048 + lane * 2;
            short8 a[16];
            #pragma unroll
            for (int ks = 0; ks < 16; ++ks) {
                unsigned long long lo = __hip_atomic_load(Ap64 + (size_t)ks * 128,
                        __ATOMIC_RELAXED, __HIP_MEMORY_SCOPE_AGENT);
                unsigned long long hi = __hip_atomic_load(Ap64 + (size_t)ks * 128 + 1,
                        __ATOMIC_RELAXED, __HIP_MEMORY_SCOPE_AGENT);
                union { unsigned long long u[2]; short8 s; } cv;
                cv.u[0] = lo; cv.u[1] = hi;
                a[ks] = cv.s;
            }
            // 4 independent accumulator chains (tile-level ILP)
            #pragma unroll
            for (int ks = 0; ks < 16; ++ks) {
                #pragma unroll
                for (int jj = 0; jj < 4; ++jj)
                    acc[jj] = __builtin_amdgcn_mfma_f32_16x16x32_bf16(
                                  a[ks], bfr[jj][ks], acc[jj], 0, 0, 0);
            }
            #pragma unroll
            for (int jj = 0; jj < 4; ++jj) {
                int g = h2 * 2 + (jj >> 1), tt = jj & 1;
                int row = g * 32 + tt * 16 + c;
                #pragma unroll
                for (int r = 0; r < 4; ++r) {
                    float v = acc[jj][r];
                    v = (g == 2) ? tanhf(v) : sigf(v);
                    gl[row * 33 + (mt * 16 + q * 4 + r)] = v;
                }
            }
            __syncthreads();
            float h4[4];
            #pragma unroll
            for (int uu = 0; uu < 4; ++uu) {
                int u = ue0 + uu;
                float iv = gl[(      u) * 33 + be];
                float fv = gl[( 32 + u) * 33 + be];
                float gv = gl[( 64 + u) * 33 + be];
                float ov = gl[( 96 + u) * 33 + be];
                creg[uu] = fv * creg[uu] + iv * gv;
                h4[uu] = ov * tanhf(creg[uu]);
            }
            if (t == PP_ - 1) {
                #pragma unroll
                for (int uu = 0; uu < 4; ++uu)
                    hbuf[(size_t)be * HH_ + nb * 32 + ue0 + uu] = h4[uu];
            } else {
                // direct register->fragment store (ks slice == nb)
                unsigned long long v = (unsigned long long)f2bf(h4[0])
                                     | ((unsigned long long)f2bf(h4[1]) << 16)
                                     | ((unsigned long long)f2bf(h4[2]) << 32)
                                     | ((unsigned long long)f2bf(h4[3]) << 48);
                size_t ui = (size_t)mt_e * 2048 + (size_t)nb * 128 + le * 2 + half;
                __hip_atomic_store((unsigned long long*)An + ui, v,
                                   __ATOMIC_RELAXED, __HIP_MEMORY_SCOPE_AGENT);
                __syncthreads();   // vmcnt(0): all 256 h stores drained
                if (tid == 0)
                    __hip_atomic_store(&flags[nb], t + 1,
                                       __ATOMIC_RELAXED, __HIP_MEMORY_SCOPE_AGENT);
                if (tid < 16) {
                    int target = t + 1;
                    while (true) {
                        int fv = __hip_atomic_load(&flags[tid],
                                __ATOMIC_RELAXED, __HIP_MEMORY_SCOPE_AGENT);
                        if (__all(fv >= target)) break;
                        __builtin_amdgcn_s_sleep(1);
                    }
                }
                __syncthreads();   // also orders gl reads vs next-step writes
            }
        }
    } else {
        float* xsT = smem;
        int* pl = (int*)(smem + 19008);
        int blk2 = blockIdx.x - 16;
        if (tid < BB_) pl[tid] = lens[tid] - 1;
        __syncthreads();
        for (int idx = tid; idx < BB_ * DD_; idx += 256) {
            int b2 = idx / DD_;
            int k = idx - b2 * DD_;
            xsT[k * 33 + b2] = seq[((size_t)pl[b2] * BB_ + b2) * DD_ + k];
        }
        __syncthreads();
        int b = tid & 31, ul = tid >> 5;
        int u = blk2 * 8 + ul;
        const float* wi = Wih_b + (size_t)u * DD_;
        const float* wg = Wih_b + (size_t)(2 * HH_ + u) * DD_;
        const float* wo = Wih_b + (size_t)(3 * HH_ + u) * DD_;
        float gi = 0.f, gg = 0.f, go = 0.f;
        #pragma unroll 4
        for (int k = 0; k < DD_; k += 4) {
            float4 w1 = *(const float4*)(wi + k);
            float4 w2 = *(const float4*)(wg + k);
            float4 w3 = *(const float4*)(wo + k);
            float x0 = xsT[(k + 0) * 33 + b];
            float x1 = xsT[(k + 1) * 33 + b];
            float x2 = xsT[(k + 2) * 33 + b];
            float x3 = xsT[(k + 3) * 33 + b];
            gi += w1.x * x0 + w1.y * x1 + w1.z * x2 + w1.w * x3;
            gg += w2.x * x0 + w2.y * x1 + w2.z * x2 + w2.w * x3;
            go += w3.x * x0 + w3.y * x1 + w3.z * x2 + w3.w * x3;
        }
        gi += bih_b[u] + bhh_b[u];
        gg += bih_b[2 * HH_ + u] + bhh_b[2 * HH_ + u];
        go += bih_b[3 * HH_ + u] + bhh_b[3 * HH_ + u];
        float cc = sigf(gi) * tanhf(gg);   // c0 = 0
        hbw[(size_t)b * HH_ + u] = sigf(go) * tanhf(cc);
    }
}

// ---------------------------------------------------------------------------
// LAUNCH 4: fused head, one block x 1024 thr (unchanged).
// ---------------------------------------------------------------------------
__global__ void __launch_bounds__(1024) head_fused_kernel(
        const float* __restrict__ hf, const float* __restrict__ hbwd,
        const int* __restrict__ lens,
        const float* __restrict__ Wfc, const float* __restrict__ bfc,
        const float* __restrict__ gamma, const float* __restrict__ beta,
        float* __restrict__ out)
{
    __shared__ float tileL[32 * 1024];   // 128 KB
    __shared__ float lmask[BB_];
    __shared__ float part[1024];
    __shared__ float ys[16][33];
    __shared__ float cstat[16];
    int tid = threadIdx.x;
    if (tid < BB_) lmask[tid] = (lens[tid] == PP_) ? 1.f : 0.f;
    __syncthreads();
    for (int j = tid; j < 32 * 1024; j += 1024) {
        int bb = j >> 10, col = j & 1023;
        float v = (col < HH_) ? hf[(size_t)bb * HH_ + col]
                              : hbwd[(size_t)bb * HH_ + col - HH_];
        tileL[j] = v * lmask[bb];
    }
    __syncthreads();
    int outi = tid & 511, half = tid >> 9;
    int i = outi >> 4, o = outi & 15;
    const float* wrow = Wfc + (size_t)o * 1024;
    float acc = 0.f;
    for (int q = 0; q < 32; ++q) {
        int j = i * 32 + q;
        #pragma unroll
        for (int bb2 = 0; bb2 < 16; ++bb2) {
            int bb = half * 16 + bb2;
            acc += tileL[bb * 1024 + j] * wrow[q * 32 + bb];
        }
    }
    part[tid] = acc;
    __syncthreads();
    if (tid < 512) ys[o][i] = part[tid] + part[tid + 512] + bfc[o];
    __syncthreads();
    if (tid < 16) {
        float mean = 0.f;
        for (int ii = 0; ii < 32; ++ii) mean += ys[tid][ii];
        mean *= (1.f / 32.f);
        float var = 0.f;
        for (int ii = 0; ii < 32; ++ii) { float d = ys[tid][ii] - mean; var += d * d; }
        var *= (1.f / 32.f);
        float inv = 1.f / sqrtf(var + 1e-5f);
        float gmm = gamma[tid], bt = beta[tid];
        float mx = -3.4e38f;
        for (int ii = 0; ii < 32; ++ii) {
            float v = gmm * (ys[tid][ii] - mean) * inv + bt;
            v = fmaxf(v, 0.f);
            ys[tid][ii] = v;
            mx = fmaxf(mx, v);
        }
        float s = 0.f;
        for (int ii = 0; ii < 32; ++ii) s += expf(ys[tid][ii] - mx);
        cstat[tid] = mx + logf(s);
    }
    __syncthreads();
    if (tid < 512) out[tid] = ys[o][i] - cstat[o];
}

extern "C" void kernel_launch(void* const* d_in, const int* in_sizes, int n_in,
                              void* d_out, int out_size, void* d_ws, size_t ws_size,
                              hipStream_t stream) {
    const int* x            = (const int*)d_in[0];
    const void* xm          = d_in[1];
    const float* x_feature  = (const float*)d_in[2];
    const int* lens         = (const int*)d_in[3];
    const float* emb    = (const float*)d_in[6];
    const float* w_attn = (const float*)d_in[7];
    const float* b_attn = (const float*)d_in[8];
    const float* Wih_f  = (const float*)d_in[9];
    const float* Whh_f  = (const float*)d_in[10];
    const float* bih_f  = (const float*)d_in[11];
    const float* bhh_f  = (const float*)d_in[12];
    const float* Wih_b  = (const float*)d_in[13];
    const float* bih_b  = (const float*)d_in[15];
    const float* bhh_b  = (const float*)d_in[16];
    const float* Wfc    = (const float*)d_in[17];
    const float* bfc    = (const float*)d_in[18];
    const float* gamma  = (const float*)d_in[19];
    const float* beta   = (const float*)d_in[20];

    float* ws    = (float*)d_ws;
    float* seq   = ws;                                    // 442368
    float* Ain   = seq + (size_t)PP_ * BB_ * DD_;         // 1572864
    float* hb    = Ain + (size_t)PP_ * BB_ * G4_;         // 16384
    float* hbuf  = hb + (size_t)BB_ * HH_;                // 16384
    float* AfA   = hbuf + (size_t)BB_ * HH_;              // 8192 (16384 bf16)
    float* AfB   = AfA + 8192;                            // 8192
    float* Bfrag = AfB + 8192;                            // 524288 (1M bf16)
    float* Wbf   = Bfrag + 524288;                        // 589824 (1.18M bf16)
    int*  flags  = (int*)(Wbf + 589824);                  // 64

    float* outp = (float*)d_out;

    prep_attn_kernel<<<dim3(2465), dim3(256), 0, stream>>>(
        x, (const unsigned int*)xm, x_feature, emb, w_attn, b_attn,
        Whh_f, (unsigned short*)Bfrag, Wih_f, (unsigned short*)Wbf,
        AfA, flags, seq);
    in_gates_mfma_kernel<<<dim3(16, 48), dim3(256), 0, stream>>>(
        seq, (const unsigned short*)Wbf, bih_f, bhh_f, Ain);
    lstm_bwd_kernel<<<dim3(80), dim3(256), 0, stream>>>(
        (unsigned short*)AfA, (unsigned short*)AfB, hbuf, Ain,
        (const unsigned short*)Bfrag, flags,
        seq, lens, Wih_b, bih_b, bhh_b, hb);
    head_fused_kernel<<<dim3(1), dim3(1024), 0, stream>>>(
        hbuf, hb, lens, Wfc, bfc, gamma, beta, outp);
}

// Round 2
// 444.030 us; speedup vs baseline: 1.0878x; 1.0878x over previous
//
#include <hip/hip_runtime.h>
#include <math.h>

#define BB_ 32   // batch
#define PP_ 24   // sentences
#define SS_ 48   // tokens
#define HH_ 512  // hidden
#define FF_ 64   // feature
#define DD_ 576  // H+F
#define G4_ 2048 // 4H

typedef __attribute__((ext_vector_type(8))) short short8;
typedef __attribute__((ext_vector_type(4))) float f32x4;

__device__ __forceinline__ float sigf(float x) { return 1.f / (1.f + expf(-x)); }

__device__ __forceinline__ unsigned short f2bf(float f) {
    unsigned int u = __float_as_uint(f);
    u += 0x7FFFu + ((u >> 16) & 1u);     // RNE
    return (unsigned short)(u >> 16);
}

// ---------------------------------------------------------------------------
// LAUNCH 1: fused [attn | weight prep | zeroing]. grid 2465 x 256.
//  blk [0,768):     attention+pooling; also writes bf16 copy of seq row
//  blk [768,1280):  Whh_f -> bf16 B-fragment order (64-block fwd tiling)
//  blk [1280,2432): Wih_f -> bf16 row-major
//  blk [2432,2464): zero AfA (h0 fragments)
//  blk 2464:        zero lstm barrier flags
// ---------------------------------------------------------------------------
__global__ void __launch_bounds__(256) prep_attn_kernel(
        const int* __restrict__ x, const unsigned int* __restrict__ maskw,
        const float* __restrict__ x_feature, const float* __restrict__ emb,
        const float* __restrict__ w_attn, const float* __restrict__ b_attn,
        const float* __restrict__ Whh, unsigned short* __restrict__ Bf,
        const float* __restrict__ Wih, unsigned short* __restrict__ Wbf,
        float* __restrict__ AfA, int* __restrict__ flags,
        float* __restrict__ seq, unsigned short* __restrict__ seqb)
{
    int blk = blockIdx.x, tid = threadIdx.x;
    if (blk < 768) {
        __shared__ float sc_s[SS_], alpha_s[SS_];
        __shared__ int vtok[SS_], vpos[SS_];
        __shared__ int nv_s, s_u8, s_f32;
        __shared__ int idx_s[SS_];
        __shared__ unsigned char msk_s[SS_];
        if (tid == 0) { s_u8 = 0; s_f32 = 0; }
        __syncthreads();
        int u8 = 0, f32 = 0;
        for (int i = tid; i < 9216; i += 256) {     // mask dtype detect (L2-hot)
            unsigned int w = maskw[i];
            if (w == 0x3F800000u) f32 = 1;
            else if (w > 1u) u8 = 1;
        }
        if (u8) s_u8 = 1;
        if (f32) s_f32 = 1;
        __syncthreads();
        int mode = s_f32 ? 2 : (s_u8 ? 1 : 0);
        int bp = blk, b = bp / PP_, p = bp % PP_;
        if (tid < SS_) {
            size_t i = (size_t)bp * SS_ + tid;
            idx_s[tid] = x[i];
            unsigned char mv;
            if (mode == 1)      mv = ((const unsigned char*)maskw)[i];
            else if (mode == 2) mv = (((const float*)maskw)[i] != 0.f);
            else                mv = (((const int*)maskw)[i] != 0);
            msk_s[tid] = mv;
        }
        __syncthreads();
        if (tid == 0) {                              // compact valid tokens
            int nv = 0;
            for (int s = 0; s < SS_; ++s)
                if (!msk_s[s]) { vtok[nv] = idx_s[s]; vpos[nv] = s; ++nv; }
            nv_s = nv;
        }
        __syncthreads();
        int nv = nv_s;
        int wave = tid >> 6, lane = tid & 63;
        float4 wa0 = ((const float4*)w_attn)[lane];        // regs, no LDS bank hits
        float4 wa1 = ((const float4*)w_attn)[64 + lane];
        for (int j = wave; j < nv; j += 4) {
            const float4* er4 = (const float4*)(emb + (size_t)vtok[j] * HH_);
            float4 v0 = er4[lane], v1 = er4[64 + lane];    // coalesced full row
            float acc = v0.x * wa0.x + v0.y * wa0.y + v0.z * wa0.z + v0.w * wa0.w
                      + v1.x * wa1.x + v1.y * wa1.y + v1.z * wa1.z + v1.w * wa1.w;
            #pragma unroll
            for (int off = 32; off > 0; off >>= 1) acc += __shfl_down(acc, off, 64);
            if (lane == 0) sc_s[j] = acc + b_attn[0];
        }
        __syncthreads();
        if (tid == 0) {                              // softmax over valid subset
            float m = -3.4e38f;
            for (int j = 0; j < nv; ++j) if (sc_s[j] > m) m = sc_s[j];
            float sum = 0.f;
            for (int j = 0; j < nv; ++j) { float a = expf(sc_s[j] - m); alpha_s[j] = a; sum += a; }
            float inv = (nv > 0) ? (1.f / sum) : 0.f;
            for (int j = 0; j < nv; ++j) alpha_s[j] *= inv;
        }
        __syncthreads();
        float acc0 = 0.f, acc1 = 0.f;
        for (int j = 0; j < nv; ++j) {               // branch-free, pipelines
            float a = alpha_s[j];
            const float* er = emb + (size_t)vtok[j] * HH_;
            acc0 += a * er[tid];
            acc1 += a * er[tid + 256];
        }
        float* orow = seq + ((size_t)p * BB_ + b) * DD_;
        unsigned short* ob = seqb + ((size_t)p * BB_ + b) * DD_;
        orow[tid] = acc0;
        orow[tid + 256] = acc1;
        ob[tid] = f2bf(acc0);
        ob[tid + 256] = f2bf(acc1);
        if (tid < FF_) {
            float accF = 0.f;
            for (int j = 0; j < nv; ++j)
                accF += x_feature[((size_t)bp * SS_ + vpos[j]) * FF_ + tid];
            orow[HH_ + tid] = accF;
            ob[HH_ + tid] = f2bf(accF);
        }
    } else if (blk < 1280) {
        int idx = (blk - 768) * 256 + tid;          // Whh -> B-fragment order (64-blk)
        int lane = idx & 63;
        int ks = (idx >> 6) & 15;
        int ti = (idx >> 10) & 1;
        int nb = idx >> 11;
        int c = lane & 15, q = lane >> 4;
        int nrow = (ti * 2 + (c >> 3)) * HH_ + nb * 8 + (c & 7);
        int k0 = ks * 32 + q * 8;
        const float* src = Whh + (size_t)nrow * HH_ + k0;
        unsigned int w0 = (unsigned int)f2bf(src[0]) | ((unsigned int)f2bf(src[1]) << 16);
        unsigned int w1 = (unsigned int)f2bf(src[2]) | ((unsigned int)f2bf(src[3]) << 16);
        unsigned int w2 = (unsigned int)f2bf(src[4]) | ((unsigned int)f2bf(src[5]) << 16);
        unsigned int w3 = (unsigned int)f2bf(src[6]) | ((unsigned int)f2bf(src[7]) << 16);
        *(uint4*)(Bf + (size_t)idx * 8) = make_uint4(w0, w1, w2, w3);
    } else if (blk < 2432) {
        int i = (blk - 1280) * 256 + tid;           // Wih -> bf16 (294912 x4)
        float4 v = ((const float4*)Wih)[i];
        ushort4 o;
        o.x = f2bf(v.x); o.y = f2bf(v.y); o.z = f2bf(v.z); o.w = f2bf(v.w);
        ((ushort4*)Wbf)[i] = o;
    } else if (blk < 2464) {
        int idx = (blk - 2432) * 256 + tid;
        if (idx < 8192) AfA[idx] = 0.f;             // h0 fragments = 0
    } else {
        if (tid < 64) flags[tid] = 0;
    }
}

// ---------------------------------------------------------------------------
// LAUNCH 2: input-gate GEMM via MFMA bf16. A is pre-converted bf16 (seqb) --
// no per-iteration f2bf VALU work.
// ---------------------------------------------------------------------------
__global__ void __launch_bounds__(256) in_gates_mfma_kernel(
        const unsigned short* __restrict__ Ab,
        const unsigned short* __restrict__ Wbf,
        const float* __restrict__ bih,
        const float* __restrict__ bhh,
        float* __restrict__ Cout)
{
    int tid = threadIdx.x, lane = tid & 63, w = tid >> 6;
    int m0 = blockIdx.y * 16;
    int nb = blockIdx.x * 128 + w * 32;
    int c = lane & 15, q = lane >> 4;
    const unsigned short* Ap  = Ab  + (size_t)(m0 + c) * DD_ + q * 8;
    const unsigned short* Bp0 = Wbf + (size_t)(nb + c) * DD_ + q * 8;
    const unsigned short* Bp1 = Bp0 + 16 * DD_;
    f32x4 acc0 = {0.f, 0.f, 0.f, 0.f}, acc1 = {0.f, 0.f, 0.f, 0.f};
    for (int k = 0; k < DD_; k += 32) {
        short8 a  = *(const short8*)(Ap  + k);
        short8 b0 = *(const short8*)(Bp0 + k);
        short8 b1 = *(const short8*)(Bp1 + k);
        acc0 = __builtin_amdgcn_mfma_f32_16x16x32_bf16(a, b0, acc0, 0, 0, 0);
        acc1 = __builtin_amdgcn_mfma_f32_16x16x32_bf16(a, b1, acc1, 0, 0, 0);
    }
    #pragma unroll
    for (int r = 0; r < 4; ++r) {
        int m = m0 + q * 4 + r;
        int n0 = nb + c, n1 = nb + 16 + c;
        Cout[(size_t)m * G4_ + n0] = acc0[r] + bih[n0] + bhh[n0];
        Cout[(size_t)m * G4_ + n1] = acc1[r] + bih[n1] + bhh[n1];
    }
}

// ---------------------------------------------------------------------------
// LAUNCH 3: fused [persistent fwd LSTM | backward one-step]. grid 128 x 256.
//  blk [0,64):   persistent LSTM, 64-block tiling (empirically best):
//                - Ain software-pipelined (prefetch t+1 during step t)
//                - wave0 owns elementwise (4 units/thread): h packs straight
//                  from registers to fragment buffer; store-drain is a
//                  wave-local s_waitcnt, NOT a block barrier
//                - 2 barriers/step (was 4)
//                - 4 independent MFMA chains
//  blk [64,128): backward-LSTM collapsed single step (unchanged).
// ---------------------------------------------------------------------------
__global__ void __launch_bounds__(256) lstm_bwd_kernel(
        unsigned short* __restrict__ AfA, unsigned short* __restrict__ AfB,
        float* __restrict__ hbuf, const float* __restrict__ Ain,
        const unsigned short* __restrict__ Bfrag, int* __restrict__ flags,
        const float* __restrict__ seq, const int* __restrict__ lens,
        const float* __restrict__ Wih_b, const float* __restrict__ bih_b,
        const float* __restrict__ bhh_b, float* __restrict__ hbw)
{
    __shared__ float smem[19040];   // union: lstm {gl 1056f} | bwd {xsT 19008f + pl}
    int tid = threadIdx.x;
    if (blockIdx.x < 64) {
        float* gl = smem;                            // [32][33]: gate-unit x batch
        int lane = tid & 63, wv = tid >> 6;
        int mt = wv & 1, ti = wv >> 1;
        int nb = blockIdx.x;
        const short8* Bp = (const short8*)Bfrag + (((size_t)nb * 2 + ti) * 16) * 64 + lane;
        short8 bfr[16];
        #pragma unroll
        for (int ks = 0; ks < 16; ++ks) bfr[ks] = Bp[ks * 64];
        int c = lane & 15, q = lane >> 4;
        int g = ti * 2 + (c >> 3), ul = c & 7;
        // wave0 elementwise ownership: batch b2s = tid>>1, units (tid&1)*4..+3
        int b2s = tid >> 1, hf2 = tid & 1;
        float creg[4] = {0.f, 0.f, 0.f, 0.f};
        // Ain software pipeline: prefetch next step during current step
        const float* ainp = Ain + (size_t)(mt * 16 + q * 4) * G4_ + g * HH_ + nb * 8 + ul;
        float ainx[4], ainn[4];
        #pragma unroll
        for (int r = 0; r < 4; ++r) ainx[r] = ainp[(size_t)r * G4_];
        for (int t = 0; t < PP_; ++t) {
            if (t + 1 < PP_) {                       // prefetch Ain[t+1] (hidden)
                const float* np = ainp + (size_t)(t + 1) * BB_ * G4_;
                #pragma unroll
                for (int r = 0; r < 4; ++r) ainn[r] = np[(size_t)r * G4_];
            }
            const unsigned short* Af = (t & 1) ? AfB : AfA;
            unsigned short* An       = (t & 1) ? AfA : AfB;
            const unsigned long long* Ap64 =
                (const unsigned long long*)Af + ((size_t)(mt * 16) * 64 + lane) * 2;
            short8 a[16];
            #pragma unroll
            for (int ks = 0; ks < 16; ++ks) {
                unsigned long long lo = __hip_atomic_load(Ap64 + (size_t)ks * 128,
                        __ATOMIC_RELAXED, __HIP_MEMORY_SCOPE_AGENT);
                unsigned long long hi = __hip_atomic_load(Ap64 + (size_t)ks * 128 + 1,
                        __ATOMIC_RELAXED, __HIP_MEMORY_SCOPE_AGENT);
                union { unsigned long long u[2]; short8 s; } cv;
                cv.u[0] = lo; cv.u[1] = hi;
                a[ks] = cv.s;
            }
            // 4 independent accumulator chains -> 1/4 serial MFMA latency
            f32x4 acA = {0.f,0.f,0.f,0.f}, acB = {0.f,0.f,0.f,0.f};
            f32x4 acC = {0.f,0.f,0.f,0.f}, acD = {0.f,0.f,0.f,0.f};
            #pragma unroll
            for (int ks = 0; ks < 16; ks += 4) {
                acA = __builtin_amdgcn_mfma_f32_16x16x32_bf16(a[ks],     bfr[ks],     acA, 0, 0, 0);
                acB = __builtin_amdgcn_mfma_f32_16x16x32_bf16(a[ks + 1], bfr[ks + 1], acB, 0, 0, 0);
                acC = __builtin_amdgcn_mfma_f32_16x16x32_bf16(a[ks + 2], bfr[ks + 2], acC, 0, 0, 0);
                acD = __builtin_amdgcn_mfma_f32_16x16x32_bf16(a[ks + 3], bfr[ks + 3], acD, 0, 0, 0);
            }
            #pragma unroll
            for (int r = 0; r < 4; ++r) {
                float v = (acA[r] + acB[r]) + (acC[r] + acD[r]) + ainx[r];
                v = (g == 2) ? tanhf(v) : sigf(v);
                gl[(g * 8 + ul) * 33 + (mt * 16 + q * 4 + r)] = v;
            }
            __syncthreads();
            if (t == PP_ - 1) {
                if (tid < 64) {
                    #pragma unroll
                    for (int uu = 0; uu < 4; ++uu) {
                        int u = hf2 * 4 + uu;
                        float iv = gl[(     u) * 33 + b2s];
                        float fv = gl[( 8 + u) * 33 + b2s];
                        float gv = gl[(16 + u) * 33 + b2s];
                        float ov = gl[(24 + u) * 33 + b2s];
                        creg[uu] = fv * creg[uu] + iv * gv;
                        hbuf[(size_t)b2s * HH_ + nb * 8 + u] = ov * tanhf(creg[uu]);
                    }
                }
            } else {
                if (tid < 64) {
                    float h4[4];
                    #pragma unroll
                    for (int uu = 0; uu < 4; ++uu) {
                        int u = hf2 * 4 + uu;
                        float iv = gl[(     u) * 33 + b2s];
                        float fv = gl[( 8 + u) * 33 + b2s];
                        float gv = gl[(16 + u) * 33 + b2s];
                        float ov = gl[(24 + u) * 33 + b2s];
                        creg[uu] = fv * creg[uu] + iv * gv;
                        h4[uu] = ov * tanhf(creg[uu]);
                    }
                    // direct register -> fragment store (same ub as verified r0)
                    unsigned long long vv = (unsigned long long)f2bf(h4[0])
                                          | ((unsigned long long)f2bf(h4[1]) << 16)
                                          | ((unsigned long long)f2bf(h4[2]) << 32)
                                          | ((unsigned long long)f2bf(h4[3]) << 48);
                    size_t ub = ((((size_t)(b2s >> 4)) * 16 + (nb >> 2)) * 64
                                 + ((b2s & 15) + 16 * (nb & 3))) * 8 + hf2 * 4;
                    __hip_atomic_store((unsigned long long*)(AfA + (An - AfA) + ub), vv,
                                       __ATOMIC_RELAXED, __HIP_MEMORY_SCOPE_AGENT);
                    // wave-local drain (only wave0 stores) -- no block barrier
                    asm volatile("s_waitcnt vmcnt(0)" ::: "memory");
                    if (tid == 0)
                        __hip_atomic_store(&flags[nb], t + 1,
                                           __ATOMIC_RELAXED, __HIP_MEMORY_SCOPE_AGENT);
                    int target = t + 1;
                    while (true) {
                        int fvv = __hip_atomic_load(&flags[tid],
                                __ATOMIC_RELAXED, __HIP_MEMORY_SCOPE_AGENT);
                        if (__all(fvv >= target)) break;
                        __builtin_amdgcn_s_sleep(1);
                    }
                }
                __syncthreads();   // releases waves 1-3; orders gl for next step
            }
            #pragma unroll
            for (int r = 0; r < 4; ++r) ainx[r] = ainn[r];
        }
    } else {
        float* xsT = smem;
        int* pl = (int*)(smem + 19008);
        int blk2 = blockIdx.x - 64;
        if (tid < BB_) pl[tid] = lens[tid] - 1;
        __syncthreads();
        for (int idx = tid; idx < BB_ * DD_; idx += 256) {
            int b2 = idx / DD_;
            int k = idx - b2 * DD_;
            xsT[k * 33 + b2] = seq[((size_t)pl[b2] * BB_ + b2) * DD_ + k];
        }
        __syncthreads();
        int b = tid & 31, ul = tid >> 5;
        int u = blk2 * 8 + ul;
        const float* wi = Wih_b + (size_t)u * DD_;
        const float* wg = Wih_b + (size_t)(2 * HH_ + u) * DD_;
        const float* wo = Wih_b + (size_t)(3 * HH_ + u) * DD_;
        float gi = 0.f, gg = 0.f, go = 0.f;
        #pragma unroll 4
        for (int k = 0; k < DD_; k += 4) {
            float4 w1 = *(const float4*)(wi + k);
            float4 w2 = *(const float4*)(wg + k);
            float4 w3 = *(const float4*)(wo + k);
            float x0 = xsT[(k + 0) * 33 + b];
            float x1 = xsT[(k + 1) * 33 + b];
            float x2 = xsT[(k + 2) * 33 + b];
            float x3 = xsT[(k + 3) * 33 + b];
            gi += w1.x * x0 + w1.y * x1 + w1.z * x2 + w1.w * x3;
            gg += w2.x * x0 + w2.y * x1 + w2.z * x2 + w2.w * x3;
            go += w3.x * x0 + w3.y * x1 + w3.z * x2 + w3.w * x3;
        }
        gi += bih_b[u] + bhh_b[u];
        gg += bih_b[2 * HH_ + u] + bhh_b[2 * HH_ + u];
        go += bih_b[3 * HH_ + u] + bhh_b[3 * HH_ + u];
        float cc = sigf(gi) * tanhf(gg);   // c0 = 0
        hbw[(size_t)b * HH_ + u] = sigf(go) * tanhf(cc);
    }
}

// ---------------------------------------------------------------------------
// LAUNCH 4: fused head, one block x 1024 thr (unchanged).
// ---------------------------------------------------------------------------
__global__ void __launch_bounds__(1024) head_fused_kernel(
        const float* __restrict__ hf, const float* __restrict__ hbwd,
        const int* __restrict__ lens,
        const float* __restrict__ Wfc, const float* __restrict__ bfc,
        const float* __restrict__ gamma, const float* __restrict__ beta,
        float* __restrict__ out)
{
    __shared__ float tileL[32 * 1024];   // 128 KB
    __shared__ float lmask[BB_];
    __shared__ float part[1024];
    __shared__ float ys[16][33];
    __shared__ float cstat[16];
    int tid = threadIdx.x;
    if (tid < BB_) lmask[tid] = (lens[tid] == PP_) ? 1.f : 0.f;
    __syncthreads();
    for (int j = tid; j < 32 * 1024; j += 1024) {
        int bb = j >> 10, col = j & 1023;
        float v = (col < HH_) ? hf[(size_t)bb * HH_ + col]
                              : hbwd[(size_t)bb * HH_ + col - HH_];
        tileL[j] = v * lmask[bb];
    }
    __syncthreads();
    int outi = tid & 511, half = tid >> 9;
    int i = outi >> 4, o = outi & 15;
    const float* wrow = Wfc + (size_t)o * 1024;
    float acc = 0.f;
    for (int q = 0; q < 32; ++q) {
        int j = i * 32 + q;
        #pragma unroll
        for (int bb2 = 0; bb2 < 16; ++bb2) {
            int bb = half * 16 + bb2;
            acc += tileL[bb * 1024 + j] * wrow[q * 32 + bb];
        }
    }
    part[tid] = acc;
    __syncthreads();
    if (tid < 512) ys[o][i] = part[tid] + part[tid + 512] + bfc[o];
    __syncthreads();
    if (tid < 16) {
        float mean = 0.f;
        for (int ii = 0; ii < 32; ++ii) mean += ys[tid][ii];
        mean *= (1.f / 32.f);
        float var = 0.f;
        for (int ii = 0; ii < 32; ++ii) { float d = ys[tid][ii] - mean; var += d * d; }
        var *= (1.f / 32.f);
        float inv = 1.f / sqrtf(var + 1e-5f);
        float gmm = gamma[tid], bt = beta[tid];
        float mx = -3.4e38f;
        for (int ii = 0; ii < 32; ++ii) {
            float v = gmm * (ys[tid][ii] - mean) * inv + bt;
            v = fmaxf(v, 0.f);
            ys[tid][ii] = v;
            mx = fmaxf(mx, v);
        }
        float s = 0.f;
        for (int ii = 0; ii < 32; ++ii) s += expf(ys[tid][ii] - mx);
        cstat[tid] = mx + logf(s);
    }
    __syncthreads();
    if (tid < 512) out[tid] = ys[o][i] - cstat[o];
}

extern "C" void kernel_launch(void* const* d_in, const int* in_sizes, int n_in,
                              void* d_out, int out_size, void* d_ws, size_t ws_size,
                              hipStream_t stream) {
    const int* x            = (const int*)d_in[0];
    const void* xm          = d_in[1];
    const float* x_feature  = (const float*)d_in[2];
    const int* lens         = (const int*)d_in[3];
    const float* emb    = (const float*)d_in[6];
    const float* w_attn = (const float*)d_in[7];
    const float* b_attn = (const float*)d_in[8];
    const float* Wih_f  = (const float*)d_in[9];
    const float* Whh_f  = (const float*)d_in[10];
    const float* bih_f  = (const float*)d_in[11];
    const float* bhh_f  = (const float*)d_in[12];
    const float* Wih_b  = (const float*)d_in[13];
    const float* bih_b  = (const float*)d_in[15];
    const float* bhh_b  = (const float*)d_in[16];
    const float* Wfc    = (const float*)d_in[17];
    const float* bfc    = (const float*)d_in[18];
    const float* gamma  = (const float*)d_in[19];
    const float* beta   = (const float*)d_in[20];

    float* ws    = (float*)d_ws;
    float* seq   = ws;                                    // 442368 f
    float* Ain   = seq + (size_t)PP_ * BB_ * DD_;         // 1572864 f
    float* hb    = Ain + (size_t)PP_ * BB_ * G4_;         // 16384 f
    float* hbuf  = hb + (size_t)BB_ * HH_;                // 16384 f
    float* AfA   = hbuf + (size_t)BB_ * HH_;              // 8192 f (16384 bf16)
    float* AfB   = AfA + 8192;                            // 8192 f
    float* Bfrag = AfB + 8192;                            // 524288 f (1M bf16)
    float* Wbf   = Bfrag + 524288;                        // 589824 f (1.18M bf16)
    int*  flags  = (int*)(Wbf + 589824);                  // 64 i (16 f)
    unsigned short* seqb = (unsigned short*)(Wbf + 589824 + 16);  // 442368 bf16

    float* outp = (float*)d_out;

    prep_attn_kernel<<<dim3(2465), dim3(256), 0, stream>>>(
        x, (const unsigned int*)xm, x_feature, emb, w_attn, b_attn,
        Whh_f, (unsigned short*)Bfrag, Wih_f, (unsigned short*)Wbf,
        AfA, flags, seq, seqb);
    in_gates_mfma_kernel<<<dim3(16, 48), dim3(256), 0, stream>>>(
        seqb, (const unsigned short*)Wbf, bih_f, bhh_f, Ain);
    lstm_bwd_kernel<<<dim3(128), dim3(256), 0, stream>>>(
        (unsigned short*)AfA, (unsigned short*)AfB, hbuf, Ain,
        (const unsigned short*)Bfrag, flags,
        seq, lens, Wih_b, bih_b, bhh_b, hb);
    head_fused_kernel<<<dim3(1), dim3(1024), 0, stream>>>(
        hbuf, hb, lens, Wfc, bfc, gamma, beta, outp);
}